// Round 3
// baseline (410.037 us; speedup 1.0000x reference)
//
#include <hip/hip_runtime.h>
#include <hip/hip_bf16.h>

// Soft decision tree, fused MFMA implementation (f16 inputs, fp32 accum).
// BATCH=8192, D_IN=512, H1=128, H2=64, OUT=8, LEAVES=64, INTERNAL=63.
// R3: A(x) in registers (mfma16 A-layout), B direct from L2 (coalesced 64B
//     segments, no LDS staging), 64-row x 8-wave blocks, 2 barriers/leaf,
//     router folded in, single prep kernel. XCD-swizzled block mapping.

typedef _Float16 f16;
typedef _Float16 f16x8 __attribute__((ext_vector_type(8)));
typedef float    f32x4 __attribute__((ext_vector_type(4)));

#define MFMA16(a, b, c) __builtin_amdgcn_mfma_f32_16x16x32_f16((a), (b), (c), 0, 0, 0)

// ---------------- workspace layout (bytes) ----------------
#define WS_XH    0u           // 8192*512 f16   = 8,388,608
#define WS_W1T   8388608u     // 64*128*512 f16 = 8,388,608   [l][n][k]
#define WS_W2T   16777216u    // 64*64*128 f16  = 1,048,576   [l][n][k]
#define WS_W3T   17825792u    // 64*16*64 f16   =   131,072   [l][n][k] (n pad 8->16, zero)
#define WS_RWT   17956864u    // 64*512 f16     =    65,536   [n][k] (row 63 zero)
#define WS_NEED  18022400u

// ---------------- fused-kernel LDS (static, 30 KB) ----------------
#define H1S 136   // h1 row stride in halfs (128+8)
#define H2S 72    // h2 row stride in halfs (64+8)
#define L_H1 0        // h1 [64][136] f16 = 17408 ; router reuses as route_s [64][68] f32
#define L_H2 17408    // h2 [64][72] f16  =  9216
#define L_P  26624    // p  [64][16] f32  =  4096
#define L_TOT 30720

// ============ one prep kernel: convert x, transpose W1/W2/W3, convert rW ============
__device__ __forceinline__ void tr_tile(const float* __restrict__ src, f16* __restrict__ dst,
                                        int K, int N, int Npad, int k0, int l, int n0, int t,
                                        float (*tile)[65]) {
  const float* s = src + ((size_t)l * K + k0) * N + n0;
#pragma unroll
  for (int i = 0; i < 16; ++i) {
    int idx = t + i * 256;
    int kk = idx >> 6, nn = idx & 63;
    float v = 0.f;
    if (n0 + nn < N) v = s[(size_t)kk * N + nn];
    tile[kk][nn] = v;
  }
  __syncthreads();
  f16* d = dst + ((size_t)l * Npad + n0) * K + k0;
#pragma unroll
  for (int i = 0; i < 16; ++i) {
    int idx = t + i * 256;
    int nn = idx >> 6, kk = idx & 63;
    if (n0 + nn < Npad) d[(size_t)nn * K + kk] = (f16)tile[kk][nn];
  }
}

__global__ __launch_bounds__(256) void prep_all(
    const float* __restrict__ x, const float* __restrict__ rW,
    const float* __restrict__ W1, const float* __restrict__ W2,
    const float* __restrict__ W3,
    f16* __restrict__ xh, f16* __restrict__ w1t, f16* __restrict__ w2t,
    f16* __restrict__ w3t, f16* __restrict__ rwt) {
  __shared__ float tile[64][65];
  const int bid = blockIdx.x;
  const int t = threadIdx.x;
  if (bid < 2048) {                       // convert x: 8192x512 fp32 -> f16, 8/thread
    size_t i = ((size_t)bid * 256 + t) * 8;
    float4 a = *(const float4*)(x + i);
    float4 b = *(const float4*)(x + i + 4);
    f16x8 h = {(f16)a.x,(f16)a.y,(f16)a.z,(f16)a.w,(f16)b.x,(f16)b.y,(f16)b.z,(f16)b.w};
    *(f16x8*)(xh + i) = h;
  } else if (bid < 3072) {                // W1 [64][512][128] -> [64][128][512]
    int rel = bid - 2048;                 // k0:8, l:64, n0:2
    tr_tile(W1, w1t, 512, 128, 128, (rel & 7) * 64, (rel >> 3) & 63, (rel >> 9) * 64, t, tile);
  } else if (bid < 3200) {                // W2 [64][128][64] -> [64][64][128]
    int rel = bid - 3072;                 // k0:2, l:64
    tr_tile(W2, w2t, 128, 64, 64, (rel & 1) * 64, rel >> 1, 0, t, tile);
  } else if (bid < 3264) {                // W3 [64][64][8] -> [64][16][64] (zero pad)
    int rel = bid - 3200;
    tr_tile(W3, w3t, 64, 8, 16, 0, rel, 0, t, tile);
  } else {                                // rW [63][512] fp32 -> f16 [64][512], row 63 zero
    int rel = bid - 3264;                 // 16 blocks
    size_t i = ((size_t)rel * 256 + t) * 8;
    int n = (int)(i >> 9);
    f16x8 h;
    if (n < 63) {
      float4 a = *(const float4*)(rW + i);
      float4 b = *(const float4*)(rW + i + 4);
      h = (f16x8){(f16)a.x,(f16)a.y,(f16)a.z,(f16)a.w,(f16)b.x,(f16)b.y,(f16)b.z,(f16)b.w};
    } else {
      h = (f16x8){0,0,0,0,0,0,0,0};
    }
    *(f16x8*)(rwt + i) = h;
  }
}

// ============ fused: router + per-leaf MLP + weighted sum ============
// 512 threads (8 waves). Block: 64 batch rows x 16 leaves. Grid 512 (XCD-swizzled).
__global__ __launch_bounds__(512, 2) void fused_tree(
    const f16* __restrict__ xh, const f16* __restrict__ w1t,
    const f16* __restrict__ w2t, const f16* __restrict__ w3t,
    const f16* __restrict__ rwt, const float* __restrict__ rb,
    const float* __restrict__ b1, const float* __restrict__ b2,
    const float* __restrict__ b3, float* __restrict__ out) {
  __shared__ char smem[L_TOT];
  f16*   h1_lds  = (f16*)(smem + L_H1);
  float* route_s = (float*)(smem + L_H1);   // [64][68] f32, dead before first h1 write
  f16*   h2_lds  = (f16*)(smem + L_H2);
  float* p_lds   = (float*)(smem + L_P);

  const int t = threadIdx.x;
  const int w = t >> 6;                 // wave 0..7
  const int L = t & 63;
  const int l16 = L & 15, quad = (L >> 4) & 3;
  const int wr = w >> 2;                // row half (0..1)
  const int wc = w & 3;                 // col quarter (0..3)

  // XCD-aware decode: 2 XCDs per leaf-group so each XCD's L2 holds one 2.1MB W1 slice
  const int bid = blockIdx.x;
  const int r8  = bid & 7;
  const int lg0 = (r8 >> 1) * 16;                  // leaf group base
  const int tileb = (bid >> 3) * 2 + (r8 & 1);     // batch tile 0..127
  const int b0 = tileb * 64;

  // ---- A (x) into registers, mfma16 A-layout: a16[s][mt] ----
  f16x8 a16[16][2];
#pragma unroll
  for (int s = 0; s < 16; ++s)
#pragma unroll
    for (int mt = 0; mt < 2; ++mt)
      a16[s][mt] = *(const f16x8*)(xh + (size_t)(b0 + wr * 32 + mt * 16 + l16) * 512 +
                                   s * 32 + quad * 8);

  // ---- router: logits for 64 nodes (B direct from L2), sigmoid -> route_s ----
  {
    f32x4 accr[2] = {{0.f,0.f,0.f,0.f},{0.f,0.f,0.f,0.f}};
    const int n = wc * 16 + l16;
    const f16* rbase = rwt + (size_t)n * 512 + quad * 8;
#pragma unroll
    for (int s = 0; s < 16; ++s) {
      f16x8 B = *(const f16x8*)(rbase + s * 32);
#pragma unroll
      for (int mt = 0; mt < 2; ++mt) accr[mt] = MFMA16(a16[s][mt], B, accr[mt]);
    }
    float rbv = (n < 63) ? rb[n] : 0.f;
#pragma unroll
    for (int mt = 0; mt < 2; ++mt)
#pragma unroll
      for (int rg = 0; rg < 4; ++rg) {
        int r = wr * 32 + mt * 16 + quad * 4 + rg;
        route_s[r * 68 + n] = 1.f / (1.f + __expf(-(accr[mt][rg] + rbv)));
      }
  }
  __syncthreads();
  // ---- path products for this block's 16 leaves -> p_lds ----
  {
    int row = t >> 3, jj = t & 7;
#pragma unroll
    for (int h = 0; h < 2; ++h) {
      int j = jj + h * 8;
      int l = lg0 + j;
      float prod = 1.f;
#pragma unroll
      for (int lev = 0; lev < 6; ++lev) {
        int node = (1 << lev) - 1 + (l >> (6 - lev));
        float d = route_s[row * 68 + node];
        prod *= ((l >> (5 - lev)) & 1) ? (1.f - d) : d;
      }
      p_lds[row * 16 + j] = prod;
    }
  }
  __syncthreads();   // route_s dead; h1 region free. p_lds visible to all.

  // ---- main per-leaf loop ----
  // GEMM1 B loads: lane-fixed offset; quarter ping-pong prefetch (8 loads in flight)
  const size_t boff = (size_t)(wc * 32 + l16) * 512 + quad * 8;
  const f16* w1b = w1t + boff;
#define LDB1(dst_, l_, q_, sp_, ct_)                                           \
  dst_ = *(const f16x8*)(w1b + ((size_t)(l_) << 16) + (ct_) * 8192 + ((q_) * 4 + (sp_)) * 32);

  f16x8 bq[2][8];
#pragma unroll
  for (int sp = 0; sp < 4; ++sp)
#pragma unroll
    for (int ct = 0; ct < 2; ++ct) LDB1(bq[0][sp * 2 + ct], lg0, 0, sp, ct)

  f32x4 acc_out = {0.f, 0.f, 0.f, 0.f};   // GEMM3 accumulator (waves 0..3)

#pragma unroll 1
  for (int li = 0; li < 16; ++li) {
    const int l = lg0 + li;

    // ---- GEMM1: X(64x512) @ W1t[l] -> acc1 (wave tile 32x32), no barriers ----
    f32x4 acc1[2][2];
#pragma unroll
    for (int mt = 0; mt < 2; ++mt)
#pragma unroll
      for (int ct = 0; ct < 2; ++ct) acc1[mt][ct] = (f32x4){0.f, 0.f, 0.f, 0.f};

#pragma unroll
    for (int q = 0; q < 4; ++q) {
      // prefetch next quarter (next leaf's q0 when q==3)
      if (q < 3) {
#pragma unroll
        for (int sp = 0; sp < 4; ++sp)
#pragma unroll
          for (int ct = 0; ct < 2; ++ct) LDB1(bq[(q + 1) & 1][sp * 2 + ct], l, q + 1, sp, ct)
      } else if (li < 15) {
#pragma unroll
        for (int sp = 0; sp < 4; ++sp)
#pragma unroll
          for (int ct = 0; ct < 2; ++ct) LDB1(bq[0][sp * 2 + ct], l + 1, 0, sp, ct)
      }
#pragma unroll
      for (int sp = 0; sp < 4; ++sp) {
        const int s = q * 4 + sp;
#pragma unroll
        for (int ct = 0; ct < 2; ++ct) {
          f16x8 B = bq[q & 1][sp * 2 + ct];
#pragma unroll
          for (int mt = 0; mt < 2; ++mt) acc1[mt][ct] = MFMA16(a16[s][mt], B, acc1[mt][ct]);
        }
      }
    }

    // ---- H1 epilogue: +b1, relu -> h1_lds ----
#pragma unroll
    for (int ct = 0; ct < 2; ++ct) {
      int n = wc * 32 + ct * 16 + l16;
      float bias = b1[l * 128 + n];
#pragma unroll
      for (int mt = 0; mt < 2; ++mt)
#pragma unroll
        for (int rg = 0; rg < 4; ++rg) {
          int r = wr * 32 + mt * 16 + quad * 4 + rg;
          float v = acc1[mt][ct][rg] + bias;
          h1_lds[r * H1S + n] = (f16)(v > 0.f ? v : 0.f);
        }
    }
    __syncthreads();   // [D] h1 visible; also orders prev-leaf h2 reads vs writes below

    // ---- GEMM2: H1(64x128) @ W2t[l] -> H2(64x64); wave tile 32x16 ----
    {
      f32x4 acc2[2] = {{0.f,0.f,0.f,0.f},{0.f,0.f,0.f,0.f}};
      const int n = wc * 16 + l16;
      const f16* w2b = w2t + (size_t)l * 8192 + (size_t)n * 128 + quad * 8;
#pragma unroll
      for (int ks = 0; ks < 4; ++ks) {
        f16x8 B = *(const f16x8*)(w2b + ks * 32);
#pragma unroll
        for (int mt = 0; mt < 2; ++mt) {
          f16x8 A = *(const f16x8*)(h1_lds + (wr * 32 + mt * 16 + l16) * H1S + ks * 32 + quad * 8);
          acc2[mt] = MFMA16(A, B, acc2[mt]);
        }
      }
      float bias = b2[l * 64 + n];
#pragma unroll
      for (int mt = 0; mt < 2; ++mt)
#pragma unroll
        for (int rg = 0; rg < 4; ++rg) {
          int r = wr * 32 + mt * 16 + quad * 4 + rg;
          float v = acc2[mt][rg] + bias;
          v = v > 0.f ? v : 0.f;
          h2_lds[r * H2S + n] = (f16)(v * p_lds[r * 16 + li]);   // fold p into H2
        }
    }
    __syncthreads();   // [E] h2 visible; also h1 reads done before next-leaf h1 writes

    // ---- GEMM3: H2'(64x64) @ W3t[l] -> acc_out (waves 0..3) ----
    if (w < 4) {
#pragma unroll
      for (int ks = 0; ks < 2; ++ks) {
        f16x8 A = *(const f16x8*)(h2_lds + (w * 16 + l16) * H2S + ks * 32 + quad * 8);
        f16x8 B = *(const f16x8*)(w3t + (size_t)l * 1024 + (size_t)l16 * 64 + ks * 32 + quad * 8);
        acc_out = MFMA16(A, B, acc_out);
      }
    }
  }

  // ---- final epilogue: + sum_li p*b3, atomicAdd into out ----
  if (w < 4 && l16 < 8) {
    float b3v[16];
#pragma unroll
    for (int li2 = 0; li2 < 16; ++li2) b3v[li2] = b3[(lg0 + li2) * 8 + l16];
#pragma unroll
    for (int rg = 0; rg < 4; ++rg) {
      int r = w * 16 + quad * 4 + rg;
      float v = acc_out[rg];
#pragma unroll
      for (int li2 = 0; li2 < 16; ++li2) v += p_lds[r * 16 + li2] * b3v[li2];
      atomicAdd(out + (size_t)(b0 + r) * 8 + l16, v);
    }
  }
#undef LDB1
}

extern "C" void kernel_launch(void* const* d_in, const int* in_sizes, int n_in,
                              void* d_out, int out_size, void* d_ws, size_t ws_size,
                              hipStream_t stream) {
  const float* x  = (const float*)d_in[0];
  const float* rW = (const float*)d_in[1];
  const float* rb = (const float*)d_in[2];
  const float* W1 = (const float*)d_in[3];
  const float* b1 = (const float*)d_in[4];
  const float* W2 = (const float*)d_in[5];
  const float* b2 = (const float*)d_in[6];
  const float* W3 = (const float*)d_in[7];
  const float* b3 = (const float*)d_in[8];
  float* out = (float*)d_out;

  if (ws_size < WS_NEED) return;

  char* ws = (char*)d_ws;
  f16* xh  = (f16*)(ws + WS_XH);
  f16* w1t = (f16*)(ws + WS_W1T);
  f16* w2t = (f16*)(ws + WS_W2T);
  f16* w3t = (f16*)(ws + WS_W3T);
  f16* rwt = (f16*)(ws + WS_RWT);

  hipMemsetAsync(d_out, 0, (size_t)out_size * sizeof(float), stream);
  prep_all<<<3280, 256, 0, stream>>>(x, rW, W1, W2, W3, xh, w1t, w2t, w3t, rwt);
  fused_tree<<<512, 512, 0, stream>>>(xh, w1t, w2t, w3t, rwt, rb, b1, b2, b3, out);
}

// Round 4
// 207.105 us; speedup vs baseline: 1.9799x; 1.9799x over previous
//
#include <hip/hip_runtime.h>
#include <hip/hip_bf16.h>

// Soft decision tree, fused MFMA implementation (f16 inputs, fp32 accum).
// BATCH=8192, D_IN=512, H1=128, H2=64, OUT=8, LEAVES=64, INTERNAL=63.
// R4: all weights pre-packed in MFMA-fragment-linear order (coalesced 1KB
//     wave loads, fixes R3's 16-segment scatter). GEMM1 = mfma32, A rows
//     0-31 in registers + rows 32-63 in swizzled LDS; one B stream feeds
//     both (halves W1 L2 traffic). Zero barriers in GEMM1; router in-kernel.

typedef _Float16 f16;
typedef _Float16 f16x8 __attribute__((ext_vector_type(8)));
typedef float    f32x4 __attribute__((ext_vector_type(4)));
typedef float    f32x16 __attribute__((ext_vector_type(16)));

#define MFMA16(a,b,c) __builtin_amdgcn_mfma_f32_16x16x32_f16((a),(b),(c),0,0,0)
#define MFMA32(a,b,c) __builtin_amdgcn_mfma_f32_32x32x16_f16((a),(b),(c),0,0,0)

// async global->LDS copy, 16 B per lane; dest = wave-uniform base + lane*16
typedef const __attribute__((address_space(1))) void gv_t;
typedef __attribute__((address_space(3))) void lv_t;
__device__ __forceinline__ void cp16(const void* g, char* lds_dst) {
  __builtin_amdgcn_global_load_lds((gv_t*)g, (lv_t*)lds_dst, 16, 0, 0);
}

// ---------------- workspace layout (bytes) ----------------
#define WS_XH    0u           // 8192*512 f16           = 8,388,608
#define WS_W1F   8388608u     // 64l*4ng*32ks*64*8 f16  = 8,388,608
#define WS_W2F   16777216u    // 64l*4nb*4ks*64*8 f16   = 1,048,576
#define WS_W3F   17825792u    // 64l*2ks*64*8 f16       =   131,072
#define WS_RWF   17956864u    // 2ng*32ks*64*8 f16      =    65,536
#define WS_NEED  18022400u

// ---------------- fused-kernel LDS (static, 49 KB) ----------------
#define L_X   0        // x rows 32..63: [32][512] f16 unpadded, unit-swizzled = 32768
#define L_H1  32768    // h1 [32][136] f16 = 8704 ; route_s overlays h1..p (64*68 f32)
#define L_H2  41472    // h2 [32][72]  f16 = 4608
#define L_P   46080    // p  [64][16]  f32 = 4096
#define L_TOT 50176

// ============ one prep kernel: convert x + fragment-pack all weights ============
__global__ __launch_bounds__(256) void prep_all(
    const float* __restrict__ x, const float* __restrict__ rW,
    const float* __restrict__ W1, const float* __restrict__ W2,
    const float* __restrict__ W3,
    f16* __restrict__ xh, f16* __restrict__ w1f, f16* __restrict__ w2f,
    f16* __restrict__ w3f, f16* __restrict__ rwf) {
  __shared__ float sb[8704];
  const int bid = blockIdx.x, t = threadIdx.x;
  if (bid < 512) {
    // ---- w1f: W1 [l][512k][128n] -> frag[(l*4+ng)*32+ks][lane][8] ----
    const int l = bid >> 3, kc = bid & 7;            // kc: 64-k chunk
    const float* src = W1 + ((size_t)l * 512 + kc * 64) * 128;
#pragma unroll
    for (int i = 0; i < 32; ++i) {
      int idx = t + i * 256;
      int k_l = idx >> 7, n = idx & 127;
      sb[n * 68 + k_l] = src[(size_t)k_l * 128 + n];
    }
    __syncthreads();
#pragma unroll
    for (int p = 0; p < 4; ++p) {
      int c = p * 4 + (t >> 6);                      // 16 combos (ng, ksl)
      int ng = c >> 2, ksl = c & 3;
      int lane = t & 63;
      int n = ng * 32 + (lane & 31);
      int k0 = ksl * 16 + (lane >> 5) * 8;
      f16x8 h;
#pragma unroll
      for (int j = 0; j < 8; ++j) h[j] = (f16)sb[n * 68 + k0 + j];
      *(f16x8*)(w1f + ((size_t)((l * 4 + ng) * 32 + kc * 4 + ksl) * 64 + lane) * 8) = h;
    }
  } else if (bid < 768) {
    // ---- xh: fp32 -> f16, row-major ----
    size_t base = (size_t)(bid - 512) * 16384;
#pragma unroll
    for (int i = 0; i < 8; ++i) {
      size_t idx = base + ((size_t)t + i * 256) * 8;
      float4 a = *(const float4*)(x + idx);
      float4 b = *(const float4*)(x + idx + 4);
      f16x8 h = {(f16)a.x,(f16)a.y,(f16)a.z,(f16)a.w,(f16)b.x,(f16)b.y,(f16)b.z,(f16)b.w};
      *(f16x8*)(xh + idx) = h;
    }
  } else if (bid < 832) {
    // ---- w2f + w3f, one leaf per block ----
    const int l = bid - 768;
    const float* src = W2 + (size_t)l * 128 * 64;
#pragma unroll
    for (int i = 0; i < 32; ++i) {
      int idx = t + i * 256;
      int k_l = idx >> 6, n = idx & 63;
      sb[n * 132 + k_l] = src[(size_t)k_l * 64 + n];
    }
    __syncthreads();
#pragma unroll
    for (int p = 0; p < 4; ++p) {
      int c = p * 4 + (t >> 6);                      // 16 combos (nb, ks)
      int nb = c >> 2, ks = c & 3;
      int lane = t & 63;
      int n = nb * 16 + (lane & 15);
      int k0 = ks * 32 + (lane >> 4) * 8;
      f16x8 h;
#pragma unroll
      for (int j = 0; j < 8; ++j) h[j] = (f16)sb[n * 132 + k0 + j];
      *(f16x8*)(w2f + ((size_t)((l * 4 + nb) * 4 + ks) * 64 + lane) * 8) = h;
    }
    if (t < 128) {                                   // w3f (n pad 8->16 zero)
      int ks = t >> 6, lane = t & 63;
      int n = lane & 15;
      int k0 = ks * 32 + (lane >> 4) * 8;
      f16x8 h;
#pragma unroll
      for (int j = 0; j < 8; ++j)
        h[j] = (n < 8) ? (f16)W3[((size_t)l * 64 + k0 + j) * 8 + n] : (f16)0.f;
      *(f16x8*)(w3f + ((size_t)(l * 2 + ks) * 64 + lane) * 8) = h;
    }
  } else {
    // ---- rwf: router W, mfma32 frags (node 63 zero) ----
    int c = (bid - 832) * 4 + (t >> 6);              // 0..63 = (ngr, ks)
    int ngr = c >> 5, ks = c & 31;
    int lane = t & 63;
    int n = ngr * 32 + (lane & 31);
    int k0 = ks * 16 + (lane >> 5) * 8;
    f16x8 h;
#pragma unroll
    for (int j = 0; j < 8; ++j)
      h[j] = (n < 63) ? (f16)rW[(size_t)n * 512 + k0 + j] : (f16)0.f;
    *(f16x8*)(rwf + ((size_t)c * 64 + lane) * 8) = h;
  }
}

// ============ fused: router + per-leaf MLP + weighted sum ============
// 256 threads (4 waves). Block: 64 batch rows (32 reg-A + 32 LDS-A) x 16 leaves.
__global__ __launch_bounds__(256, 2) void fused_tree(
    const f16* __restrict__ xh, const f16* __restrict__ w1f,
    const f16* __restrict__ w2f, const f16* __restrict__ w3f,
    const f16* __restrict__ rwf, const float* __restrict__ rb,
    const float* __restrict__ b1, const float* __restrict__ b2,
    const float* __restrict__ b3, float* __restrict__ out) {
  __shared__ char smem[L_TOT];
  f16*   x_lds   = (f16*)(smem + L_X);
  f16*   h1_lds  = (f16*)(smem + L_H1);
  float* route_s = (float*)(smem + L_H1);   // [64][68] f32, dead before h1 use
  f16*   h2_lds  = (f16*)(smem + L_H2);
  float* p_lds   = (float*)(smem + L_P);

  const int t = threadIdx.x;
  const int w = t >> 6, L = t & 63;
  const int l16 = L & 15, quad = L >> 4;
  const int r31 = L & 31, kp = L >> 5;

  // XCD-aware decode: 2 XCDs per leaf-group -> leaf W1 slice L2-resident
  const int bid = blockIdx.x;
  const int r8 = bid & 7;
  const int lg0 = (r8 >> 1) * 16;
  const int btp = (bid >> 3) * 2 + (r8 & 1);     // 0..127
  const int b0 = btp * 64;

  // ---- stage x rows b0+32..63 into swizzled LDS (1 row per wave-issue) ----
#pragma unroll
  for (int j = 0; j < 8; ++j) {
    int r = w * 8 + j;
    int u = (L & 56) | ((L & 7) ^ (r & 7));
    cp16(xh + (size_t)(b0 + 32 + r) * 512 + u * 8, smem + r * 1024);
  }
  // ---- A0: rows b0..b0+31 in registers, mfma32 A-layout ----
  f16x8 a0[32];
#pragma unroll
  for (int ks = 0; ks < 32; ++ks)
    a0[ks] = *(const f16x8*)(xh + (size_t)(b0 + r31) * 512 + ks * 16 + kp * 8);
  __syncthreads();

  // ---- router: waves 0,1 -> bt0 (reg A), waves 2,3 -> bt1 (LDS A) ----
  {
    const int btr = w >> 1, ngr = w & 1;
    f32x16 accr;
#pragma unroll
    for (int i = 0; i < 16; ++i) accr[i] = 0.f;
    const f16* rbase = rwf + (size_t)(ngr * 32) * 512 + (size_t)L * 8;
#pragma unroll
    for (int ks = 0; ks < 32; ++ks) {
      f16x8 B = *(const f16x8*)(rbase + (size_t)ks * 512);
      f16x8 A;
      if (btr == 0) A = a0[ks];
      else {
        int u = ks * 2 + kp;
        A = *(const f16x8*)(x_lds + r31 * 512 + ((u & 56) | ((u & 7) ^ (r31 & 7))) * 8);
      }
      accr = MFMA32(A, B, accr);
    }
    int node = ngr * 32 + r31;
    float rbv = (node < 63) ? rb[node] : 0.f;
#pragma unroll
    for (int reg = 0; reg < 16; ++reg) {
      int rr = btr * 32 + (reg & 3) + 8 * (reg >> 2) + 4 * kp;
      route_s[rr * 68 + node] = 1.f / (1.f + __expf(-(accr[reg] + rbv)));
    }
  }
  __syncthreads();
  // ---- path products (into regs, then store after sync: p overlays route_s) ----
  float prod[4];
  {
    int row = t >> 2, j0 = t & 3;
#pragma unroll
    for (int i = 0; i < 4; ++i) {
      int l = lg0 + j0 * 4 + i;
      float pr = 1.f;
#pragma unroll
      for (int lev = 0; lev < 6; ++lev) {
        int node = (1 << lev) - 1 + (l >> (6 - lev));
        float d = route_s[row * 68 + node];
        pr *= ((l >> (5 - lev)) & 1) ? (1.f - d) : d;
      }
      prod[i] = pr;
    }
  }
  __syncthreads();
  {
    int row = t >> 2, j0 = t & 3;
#pragma unroll
    for (int i = 0; i < 4; ++i) p_lds[row * 16 + j0 * 4 + i] = prod[i];
  }
  __syncthreads();

  // ---- main leaf loop ----
  const f16* w1base = w1f + ((size_t)(lg0 * 4 + w) * 32) * 512 + (size_t)L * 8;
  f16x8 bq[2][4];
#pragma unroll
  for (int s = 0; s < 4; ++s) bq[0][s] = *(const f16x8*)(w1base + (size_t)s * 512);

  f32x4 acc_out = {0.f, 0.f, 0.f, 0.f};
  const int mt = w >> 1, nt2 = w & 1;     // GEMM2 wave mapping

#pragma unroll 1
  for (int li = 0; li < 16; ++li) {
    const int l = lg0 + li;
    const size_t leafoff = (size_t)li * 65536;

    // ---- GEMM1: X(64x512) @ W1[l] -> H1(64x128); no barriers, B stream ----
    f32x16 acc1r, acc1l;
#pragma unroll
    for (int i = 0; i < 16; ++i) { acc1r[i] = 0.f; acc1l[i] = 0.f; }

#pragma unroll
    for (int q = 0; q < 8; ++q) {
      size_t nxt = (q < 7) ? (leafoff + (size_t)(q + 1) * 2048)
                           : ((li < 15) ? (leafoff + 65536) : (leafoff + 7 * 2048));
#pragma unroll
      for (int s = 0; s < 4; ++s)
        bq[(q + 1) & 1][s] = *(const f16x8*)(w1base + nxt + (size_t)s * 512);
#pragma unroll
      for (int s = 0; s < 4; ++s) {
        int ks = q * 4 + s;
        int u = ks * 2 + kp;
        f16x8 A1 = *(const f16x8*)(x_lds + r31 * 512 + ((u & 56) | ((u & 7) ^ (r31 & 7))) * 8);
        acc1r = MFMA32(a0[ks], bq[q & 1][s], acc1r);
        acc1l = MFMA32(A1, bq[q & 1][s], acc1l);
      }
    }

    // B2/B3 frag loads (coalesced; reused for both batch halves)
    f16x8 bw2[2][4];
#pragma unroll
    for (int n16 = 0; n16 < 2; ++n16)
#pragma unroll
      for (int ks = 0; ks < 4; ++ks)
        bw2[n16][ks] = *(const f16x8*)(w2f + ((size_t)((l * 4 + nt2 * 2 + n16) * 4 + ks) * 64 + L) * 8);
    f16x8 bw3[2];
#pragma unroll
    for (int ks = 0; ks < 2; ++ks)
      bw3[ks] = *(const f16x8*)(w3f + ((size_t)(l * 2 + ks) * 64 + L) * 8);

    const int n1 = w * 32 + r31;
    const float bias1 = b1[l * 128 + n1];

    // ---- h1 <- bt0 ----
#pragma unroll
    for (int reg = 0; reg < 16; ++reg) {
      int rr = (reg & 3) + 8 * (reg >> 2) + 4 * kp;
      float v = acc1r[reg] + bias1;
      h1_lds[rr * 136 + n1] = (f16)(v > 0.f ? v : 0.f);
    }
    __syncthreads();   // S1: h1(bt0) visible

#define GEMM2_BT(btv)                                                          \
    {                                                                          \
      f32x4 acc2[2] = {{0.f,0.f,0.f,0.f},{0.f,0.f,0.f,0.f}};                   \
      _Pragma("unroll")                                                        \
      for (int ks = 0; ks < 4; ++ks) {                                         \
        f16x8 A = *(const f16x8*)(h1_lds + (mt * 16 + l16) * 136 + ks * 32 + quad * 8); \
        _Pragma("unroll")                                                      \
        for (int n16 = 0; n16 < 2; ++n16) acc2[n16] = MFMA16(A, bw2[n16][ks], acc2[n16]); \
      }                                                                        \
      _Pragma("unroll")                                                        \
      for (int n16 = 0; n16 < 2; ++n16) {                                      \
        int n2 = nt2 * 32 + n16 * 16 + l16;                                    \
        float bias2 = b2[l * 64 + n2];                                         \
        _Pragma("unroll")                                                      \
        for (int rg = 0; rg < 4; ++rg) {                                       \
          int r2 = mt * 16 + quad * 4 + rg;                                    \
          float v = acc2[n16][rg] + bias2;                                     \
          v = v > 0.f ? v : 0.f;                                               \
          h2_lds[r2 * 72 + n2] = (f16)(v * p_lds[((btv) * 32 + r2) * 16 + li]); \
        }                                                                      \
      }                                                                        \
    }

    GEMM2_BT(0)
    __syncthreads();   // S2: h2(bt0) visible; h1 reads done

    if (w < 2) {       // GEMM3 bt0 (waves 0,1)
#pragma unroll
      for (int ks = 0; ks < 2; ++ks) {
        f16x8 A = *(const f16x8*)(h2_lds + ((w & 1) * 16 + l16) * 72 + ks * 32 + quad * 8);
        acc_out = MFMA16(A, bw3[ks], acc_out);
      }
    }
    // ---- h1 <- bt1 (disjoint from h2 reads above) ----
#pragma unroll
    for (int reg = 0; reg < 16; ++reg) {
      int rr = (reg & 3) + 8 * (reg >> 2) + 4 * kp;
      float v = acc1l[reg] + bias1;
      h1_lds[rr * 136 + n1] = (f16)(v > 0.f ? v : 0.f);
    }
    __syncthreads();   // S3: h1(bt1) visible; h2(bt0) reads done

    GEMM2_BT(1)
    __syncthreads();   // S4: h2(bt1) visible; h1 reads done

    if (w >= 2) {      // GEMM3 bt1 (waves 2,3)
#pragma unroll
      for (int ks = 0; ks < 2; ++ks) {
        f16x8 A = *(const f16x8*)(h2_lds + ((w & 1) * 16 + l16) * 72 + ks * 32 + quad * 8);
        acc_out = MFMA16(A, bw3[ks], acc_out);
      }
    }
    // next-leaf h1 writes are gated by S1-next barrier arrival of all waves
#undef GEMM2_BT
  }

  // ---- final epilogue: + sum_li p*b3, atomicAdd ----
  if (l16 < 8) {
    const int btf = w >> 1, mtf = w & 1;
    float b3v[16];
#pragma unroll
    for (int li2 = 0; li2 < 16; ++li2) b3v[li2] = b3[(lg0 + li2) * 8 + l16];
#pragma unroll
    for (int rg = 0; rg < 4; ++rg) {
      int rloc = btf * 32 + mtf * 16 + quad * 4 + rg;
      float v = acc_out[rg];
#pragma unroll
      for (int li2 = 0; li2 < 16; ++li2) v += p_lds[rloc * 16 + li2] * b3v[li2];
      atomicAdd(out + (size_t)(b0 + rloc) * 8 + l16, v);
    }
  }
}

extern "C" void kernel_launch(void* const* d_in, const int* in_sizes, int n_in,
                              void* d_out, int out_size, void* d_ws, size_t ws_size,
                              hipStream_t stream) {
  const float* x  = (const float*)d_in[0];
  const float* rW = (const float*)d_in[1];
  const float* rb = (const float*)d_in[2];
  const float* W1 = (const float*)d_in[3];
  const float* b1 = (const float*)d_in[4];
  const float* W2 = (const float*)d_in[5];
  const float* b2 = (const float*)d_in[6];
  const float* W3 = (const float*)d_in[7];
  const float* b3 = (const float*)d_in[8];
  float* out = (float*)d_out;

  if (ws_size < WS_NEED) return;

  char* ws = (char*)d_ws;
  f16* xh  = (f16*)(ws + WS_XH);
  f16* w1f = (f16*)(ws + WS_W1F);
  f16* w2f = (f16*)(ws + WS_W2F);
  f16* w3f = (f16*)(ws + WS_W3F);
  f16* rwf = (f16*)(ws + WS_RWF);

  hipMemsetAsync(d_out, 0, (size_t)out_size * sizeof(float), stream);
  prep_all<<<848, 256, 0, stream>>>(x, rW, W1, W2, W3, xh, w1f, w2f, w3f, rwf);
  fused_tree<<<512, 256, 0, stream>>>(xh, w1f, w2f, w3f, rwf, rb, b1, b2, b3, out);
}